// Round 3
// baseline (485.875 us; speedup 1.0000x reference)
//
#include <hip/hip_runtime.h>

// Deterministic hard voxelization (mmcv hard_voxelize_forward) for MI355X.
//
// Pipeline (no sorting):
//   K1  k_insert : per point -> voxel coord -> hash-table insert (atomicCAS)
//                  + atomicMin(first-point-index per voxel); store hash slot.
//   K2a k_scan1  : block partial sums of "leader" flags (minidx[h]==i).
//   K2b k_scan2  : single-block exclusive scan of block sums; writes voxel_num.
//   K2c k_scan3  : re-scan; leader rank r = voxel slot; tag into minidx
//                  (0x80000000|r); r<MAXV writes coors[r]=(z,y,x).
//   K3  k_bucket : candidate points (slot<MAXV) appended to 64-deep buckets.
//   K4  k_emit   : 32 lanes per slot: rank-select bucket entries by original
//                  index, write ALL 32 rows (zero-fill) + num_points.
//
// Slot assignment logic: slot(v) = #voxels whose first point appears earlier
// = exclusive prefix sum of per-point leader flags (leader <=> minidx[h]==i),
// which equals the reference's argsort-of-group-first-appearance ranks.
//
// Output layout (all float32): voxels[120000*32*4] | coors[120000*3] |
//                              num_points[120000] | voxel_num[1]

#define GX 1408
#define GY 1600
#define GZ 40
#define MAXV 120000
#define MAXP 32
#define HBITS 22
#define HSIZE (1u << HBITS)      // 4,194,304 slots; ~1.98M keys -> load 0.47
#define HMASK (HSIZE - 1u)
#define ITEMS 16
#define SCAN_BS 256
#define CHUNK (SCAN_BS * ITEMS)  // 4096 points per scan block
#define BUCKET_CAP 64
#define EMIT_SLOTS_PER_BLOCK 8   // 8 slots x 32 lanes = 256 threads

__device__ __forceinline__ unsigned hash_lin(int lin) {
  unsigned h = (unsigned)lin * 2654435761u;
  h ^= h >> 15;
  return h & HMASK;
}

__global__ __launch_bounds__(256) void k_insert(const float4* __restrict__ pts,
                                                int* __restrict__ keys,
                                                unsigned* __restrict__ minidx,
                                                int* __restrict__ hslot, int n) {
  int i = blockIdx.x * blockDim.x + threadIdx.x;
  if (i >= n) return;
  float4 p = pts[i];
  // Must match JAX f32 ops bit-exactly: (p - lo) / vs, floor, cast.
  // No fast-math: division must stay IEEE (not strength-reduced to *20).
  int cx = (int)floorf((p.x - 0.0f)   / 0.05f);
  int cy = (int)floorf((p.y - -40.0f) / 0.05f);
  int cz = (int)floorf((p.z - -3.0f)  / 0.1f);
  bool valid = (cx >= 0) && (cx < GX) && (cy >= 0) && (cy < GY) && (cz >= 0) && (cz < GZ);
  if (!valid) { hslot[i] = -1; return; }
  int lin = cz * (GX * GY) + cy * GX + cx;
  unsigned h = hash_lin(lin);
  while (true) {
    int old = atomicCAS(&keys[h], -1, lin);
    if (old == -1 || old == lin) break;
    h = (h + 1) & HMASK;
  }
  atomicMin(&minidx[h], (unsigned)i);
  hslot[i] = (int)h;
}

__global__ __launch_bounds__(SCAN_BS) void k_scan1(const int* __restrict__ hslot,
                                                   const unsigned* __restrict__ minidx,
                                                   int* __restrict__ blocksums, int n) {
  __shared__ int sm[SCAN_BS];
  int base = blockIdx.x * CHUNK + threadIdx.x * ITEMS;
  int cnt = 0;
#pragma unroll
  for (int j = 0; j < ITEMS; ++j) {
    int i = base + j;
    if (i < n) {
      int h = hslot[i];
      if (h >= 0 && minidx[h] == (unsigned)i) cnt++;
    }
  }
  sm[threadIdx.x] = cnt;
  __syncthreads();
  for (int off = SCAN_BS / 2; off > 0; off >>= 1) {
    if (threadIdx.x < off) sm[threadIdx.x] += sm[threadIdx.x + off];
    __syncthreads();
  }
  if (threadIdx.x == 0) blocksums[blockIdx.x] = sm[0];
}

// Single block of 512 threads: exclusive scan of <=512 block sums. nb<=512 required.
__global__ __launch_bounds__(512) void k_scan2(int* __restrict__ blocksums,
                                               float* __restrict__ voxnum_out, int nb) {
  __shared__ int sm[512];
  int t = threadIdx.x;
  int v = (t < nb) ? blocksums[t] : 0;
  sm[t] = v;
  __syncthreads();
  for (int off = 1; off < 512; off <<= 1) {
    int x = sm[t];
    int add = (t >= off) ? sm[t - off] : 0;
    __syncthreads();
    sm[t] = x + add;
    __syncthreads();
  }
  if (t < nb) blocksums[t] = sm[t] - v;  // exclusive block offsets
  if (t == 511) {
    int total = sm[511];
    *voxnum_out = (float)(total < MAXV ? total : MAXV);
  }
}

__global__ __launch_bounds__(SCAN_BS) void k_scan3(const int* __restrict__ hslot,
                                                   unsigned* __restrict__ minidx,
                                                   const int* __restrict__ keys,
                                                   const int* __restrict__ blockoffs,
                                                   float* __restrict__ out_coors, int n) {
  __shared__ int sm[SCAN_BS];
  int base = blockIdx.x * CHUNK + threadIdx.x * ITEMS;
  unsigned mbits = 0;
  int cnt = 0;
#pragma unroll
  for (int j = 0; j < ITEMS; ++j) {
    int i = base + j;
    if (i < n) {
      int h = hslot[i];
      // Tag (0x80000000|r) can never equal a point index (<2^31), and only
      // the unique leader of h writes the tag, after its own read. Race-safe.
      if (h >= 0 && minidx[h] == (unsigned)i) { mbits |= (1u << j); cnt++; }
    }
  }
  sm[threadIdx.x] = cnt;
  __syncthreads();
  for (int off = 1; off < SCAN_BS; off <<= 1) {  // Hillis-Steele inclusive
    int x = sm[threadIdx.x];
    int add = (threadIdx.x >= off) ? sm[threadIdx.x - off] : 0;
    __syncthreads();
    sm[threadIdx.x] = x + add;
    __syncthreads();
  }
  int r = blockoffs[blockIdx.x] + (sm[threadIdx.x] - cnt);  // exclusive rank
#pragma unroll
  for (int j = 0; j < ITEMS; ++j) {
    if (mbits & (1u << j)) {
      int i = base + j;
      int h = hslot[i];
      minidx[h] = 0x80000000u | (unsigned)r;
      if (r < MAXV) {
        int lin = keys[h];
        int x = lin % GX;
        int t = lin / GX;
        int y = t % GY;
        int z = t / GY;
        out_coors[r * 3 + 0] = (float)z;
        out_coors[r * 3 + 1] = (float)y;
        out_coors[r * 3 + 2] = (float)x;
      }
      r++;
    }
  }
}

__global__ __launch_bounds__(256) void k_bucket(const int* __restrict__ hslot,
                                                const unsigned* __restrict__ minidx,
                                                int* __restrict__ bcnt,
                                                int* __restrict__ bucket, int n) {
  int i = blockIdx.x * blockDim.x + threadIdx.x;
  if (i >= n) return;
  int h = hslot[i];
  if (h < 0) return;
  unsigned r = minidx[h] & 0x7fffffffu;  // all live slots are tagged after k_scan3
  if (r < MAXV) {
    int pos = atomicAdd(&bcnt[r], 1);
    if (pos < BUCKET_CAP) bucket[r * BUCKET_CAP + pos] = i;
  }
}

// 32 lanes per slot. Lane r selects the bucket entry of rank r (ascending
// original index) and writes voxels[s][r]; unused rows get zeros. Writes are
// fully coalesced: lane r stores 16B at (s*32+r)*16. Bucket entries are
// staged on demand (avg occupancy ~1 point/slot; avoids reading 30 MB).
__global__ __launch_bounds__(256) void k_emit(const float4* __restrict__ pts,
                                              const int* __restrict__ bcnt,
                                              const int* __restrict__ bucket,
                                              float4* __restrict__ out_voxels,
                                              float* __restrict__ out_npts) {
  __shared__ int sb[EMIT_SLOTS_PER_BLOCK][BUCKET_CAP];
  int grp = threadIdx.x >> 5;           // slot group within block
  int r = threadIdx.x & 31;             // row / lane within group
  int s = blockIdx.x * EMIT_SLOTS_PER_BLOCK + grp;
  if (s >= MAXV) return;                // grid sized exactly; keep for safety

  int nfull = bcnt[s];
  int nc = nfull < BUCKET_CAP ? nfull : BUCKET_CAP;
  int m = nfull < MAXP ? nfull : MAXP;

  // On-demand staging: only the first nc entries are ever compared.
  const int* brow = bucket + (size_t)s * BUCKET_CAP;
  if (r < nc) sb[grp][r] = brow[r];
  if (r + 32 < nc) sb[grp][r + 32] = brow[r + 32];
  __syncthreads();

  float4 row = make_float4(0.f, 0.f, 0.f, 0.f);
  if (r < m) {
    // Find entry whose rank (count of smaller entries) == r. Entries unique.
    int mine = -1;
    for (int j = 0; j < nc; ++j) {
      int ej = sb[grp][j];
      int rank = 0;
      for (int k = 0; k < nc; ++k) rank += (sb[grp][k] < ej) ? 1 : 0;
      if (rank == r) mine = ej;
    }
    row = pts[mine];
  }
  out_voxels[(size_t)s * MAXP + r] = row;
  if (r == 0) out_npts[s] = (float)m;
}

extern "C" void kernel_launch(void* const* d_in, const int* in_sizes, int n_in,
                              void* d_out, int out_size, void* d_ws, size_t ws_size,
                              hipStream_t stream) {
  const float4* pts = (const float4*)d_in[0];
  int n = in_sizes[0] / 4;  // 2,000,000
  float* out = (float*)d_out;

  // Workspace layout (bytes); total ~71.3 MB
  char* ws = (char*)d_ws;
  int* keys        = (int*)(ws);                                   // 16 MB
  unsigned* minidx = (unsigned*)(ws + (size_t)HSIZE * 4);          // 16 MB
  int* hslot       = (int*)(ws + (size_t)HSIZE * 8);               // 8 MB
  int* blocksums   = (int*)(ws + (size_t)HSIZE * 8 + (size_t)n * 4);          // 16 KB reserved
  int* bcnt        = (int*)(ws + (size_t)HSIZE * 8 + (size_t)n * 4 + 16384);  // 480 KB
  int* bucket      = (int*)(ws + (size_t)HSIZE * 8 + (size_t)n * 4 + 16384 + (size_t)MAXV * 4);  // 30.7 MB

  float* out_voxels = out;                                     // 120000*32*4
  float* out_coors  = out + (size_t)MAXV * MAXP * 4;           // 120000*3
  float* out_npts   = out_coors + (size_t)MAXV * 3;            // 120000
  float* out_voxnum = out_npts + MAXV;                         // 1

  // keys=-1 and minidx=0xFFFFFFFF share one 0xFF memset (adjacent regions).
  hipMemsetAsync(keys, 0xFF, (size_t)HSIZE * 8, stream);
  hipMemsetAsync(bcnt, 0, (size_t)MAXV * 4, stream);
  // Only the small tail needs zeroing: coors (npts/voxnum overwritten anyway).
  hipMemsetAsync(out_coors, 0, ((size_t)MAXV * 3 + MAXV + 1) * sizeof(float), stream);

  int nb_pts = (n + 255) / 256;
  int nb_scan = (n + CHUNK - 1) / CHUNK;  // 489 for n=2e6 (must be <=512)

  k_insert<<<nb_pts, 256, 0, stream>>>(pts, keys, minidx, hslot, n);
  k_scan1<<<nb_scan, SCAN_BS, 0, stream>>>(hslot, minidx, blocksums, n);
  k_scan2<<<1, 512, 0, stream>>>(blocksums, out_voxnum, nb_scan);
  k_scan3<<<nb_scan, SCAN_BS, 0, stream>>>(hslot, minidx, keys, blocksums, out_coors, n);
  k_bucket<<<nb_pts, 256, 0, stream>>>(hslot, minidx, bcnt, bucket, n);
  k_emit<<<(MAXV + EMIT_SLOTS_PER_BLOCK - 1) / EMIT_SLOTS_PER_BLOCK, 256, 0, stream>>>(
      pts, bcnt, bucket, (float4*)out_voxels, out_npts);
}

// Round 4
// 338.061 us; speedup vs baseline: 1.4372x; 1.4372x over previous
//
#include <hip/hip_runtime.h>

// Deterministic hard voxelization (mmcv hard_voxelize_forward) for MI355X.
//
// v3: packed u64 hash entries {key:hi32, minidx:lo32} -> ONE random atomic
// per point; 4-point batched CAS issue for MLP; lead[]/rank[] arrays remove
// the scan3/bucket random gathers over the 32MB table.
//
// Pipeline:
//   K1  k_insert : point -> voxel -> single u64 CAS claim {lin,i}; same-key
//                  -> u64-CAS min loop. hslot[i] = final slot.
//   K2a k_scan1  : lead[i] = entry minidx (random gather, 1 per point);
//                  leader flag = (lead[i]==i); block sums.
//   K2b k_scan2  : single-block exclusive scan of 489 block sums; voxel_num.
//   K2c k_scan3  : leaders from lead[i]==i (streaming); rank r per leader
//                  written over hslot[i]; r<MAXV: gather key, write coors.
//   K3  k_bucket : r = rank[lead[i]]; r<MAXV -> append i to bucket[r].
//   K4  k_emit   : 32 lanes/slot: rank-select by original index, write all
//                  32 rows (zero-fill) + num_points.
//
// Output (float32): voxels[120000*32*4] | coors[120000*3] | npts[120000] | voxel_num[1]

#define GX 1408
#define GY 1600
#define GZ 40
#define MAXV 120000
#define MAXP 32
#define HBITS 22
#define HSIZE (1u << HBITS)      // 4,194,304 slots; ~1.98M keys -> load 0.47
#define HMASK (HSIZE - 1u)
#define ITEMS 16
#define SCAN_BS 256
#define CHUNK (SCAN_BS * ITEMS)  // 4096 points per scan block
#define IB 4                     // points per thread in insert/bucket
#define EMIT_SPB 8               // 8 slots x 32 lanes = 256 threads

typedef unsigned long long u64;
typedef unsigned int u32;
#define EMPTY64 0xFFFFFFFFFFFFFFFFull

__device__ __forceinline__ u32 hash_lin(int lin) {
  u32 h = (u32)lin * 2654435761u;
  h ^= h >> 15;
  return h & HMASK;
}

__global__ __launch_bounds__(256) void k_insert(const float4* __restrict__ pts,
                                                u64* __restrict__ ent,
                                                int* __restrict__ hslot, int n) {
  int base = blockIdx.x * (256 * IB) + threadIdx.x;
  int lin[IB]; u32 h[IB]; bool ok[IB]; u64 old[IB];

  // Phase 1: compute voxel coords (must match JAX f32 ops bit-exactly; no fast-math).
#pragma unroll
  for (int j = 0; j < IB; ++j) {
    int i = base + j * 256;
    ok[j] = false;
    lin[j] = 0; h[j] = 0;
    if (i < n) {
      float4 p = pts[i];
      int cx = (int)floorf((p.x - 0.0f)   / 0.05f);
      int cy = (int)floorf((p.y - -40.0f) / 0.05f);
      int cz = (int)floorf((p.z - -3.0f)  / 0.1f);
      if ((cx >= 0) && (cx < GX) && (cy >= 0) && (cy < GY) && (cz >= 0) && (cz < GZ)) {
        lin[j] = cz * (GX * GY) + cy * GX + cx;
        h[j] = hash_lin(lin[j]);
        ok[j] = true;
      }
    }
  }

  // Phase 2: optimistic first CAS for all IB points back-to-back (MLP).
#pragma unroll
  for (int j = 0; j < IB; ++j) {
    if (ok[j]) {
      u64 des = ((u64)(u32)lin[j] << 32) | (u32)(base + j * 256);
      old[j] = atomicCAS(&ent[h[j]], EMPTY64, des);
    }
  }

  // Phase 3: resolve (rare probe continuation / same-key min).
#pragma unroll
  for (int j = 0; j < IB; ++j) {
    int i = base + j * 256;
    if (i >= n) continue;
    if (!ok[j]) { hslot[i] = -1; continue; }
    u32 i_u = (u32)i;
    u64 des = ((u64)(u32)lin[j] << 32) | i_u;
    u32 hh = h[j];
    u64 o = old[j];
    while (true) {
      if (o == EMPTY64) break;                    // claimed; minidx=i already
      if ((u32)(o >> 32) == (u32)lin[j]) {        // same key: CAS-min low word
        while ((u32)o > i_u) {
          u64 want = (o & 0xFFFFFFFF00000000ull) | (u64)i_u;
          u64 prev = atomicCAS(&ent[hh], o, want);
          if (prev == o) break;
          o = prev;
        }
        break;
      }
      hh = (hh + 1) & HMASK;                      // occupied by other key: probe on
      o = atomicCAS(&ent[hh], EMPTY64, des);
    }
    hslot[i] = (int)hh;
  }
}

__global__ __launch_bounds__(SCAN_BS) void k_scan1(const int* __restrict__ hslot,
                                                   const u32* __restrict__ entw,
                                                   int* __restrict__ lead,
                                                   int* __restrict__ blocksums, int n) {
  __shared__ int sm[SCAN_BS];
  int base = blockIdx.x * CHUNK + threadIdx.x * ITEMS;
  int cnt = 0;
#pragma unroll
  for (int j = 0; j < ITEMS; ++j) {
    int i = base + j;
    if (i < n) {
      int h = hslot[i];
      int L = -1;
      if (h >= 0) L = (int)entw[2u * (u32)h];     // low word = final min index
      lead[i] = L;
      if (L == i) cnt++;
    }
  }
  sm[threadIdx.x] = cnt;
  __syncthreads();
  for (int off = SCAN_BS / 2; off > 0; off >>= 1) {
    if (threadIdx.x < off) sm[threadIdx.x] += sm[threadIdx.x + off];
    __syncthreads();
  }
  if (threadIdx.x == 0) blocksums[blockIdx.x] = sm[0];
}

// Single block of 512 threads: exclusive scan of <=512 block sums.
__global__ __launch_bounds__(512) void k_scan2(int* __restrict__ blocksums,
                                               float* __restrict__ voxnum_out, int nb) {
  __shared__ int sm[512];
  int t = threadIdx.x;
  int v = (t < nb) ? blocksums[t] : 0;
  sm[t] = v;
  __syncthreads();
  for (int off = 1; off < 512; off <<= 1) {
    int x = sm[t];
    int add = (t >= off) ? sm[t - off] : 0;
    __syncthreads();
    sm[t] = x + add;
    __syncthreads();
  }
  if (t < nb) blocksums[t] = sm[t] - v;  // exclusive block offsets
  if (t == 511) {
    int total = sm[511];
    *voxnum_out = (float)(total < MAXV ? total : MAXV);
  }
}

// Leaders from lead[i]==i (streaming). rank written over hslot (aliased).
__global__ __launch_bounds__(SCAN_BS) void k_scan3(const int* __restrict__ lead,
                                                   int* __restrict__ hslot_rank,
                                                   const u32* __restrict__ entw,
                                                   const int* __restrict__ blockoffs,
                                                   float* __restrict__ out_coors, int n) {
  __shared__ int sm[SCAN_BS];
  int base = blockIdx.x * CHUNK + threadIdx.x * ITEMS;
  u32 mbits = 0;
  int cnt = 0;
#pragma unroll
  for (int j = 0; j < ITEMS; ++j) {
    int i = base + j;
    if (i < n && lead[i] == i) { mbits |= (1u << j); cnt++; }
  }
  sm[threadIdx.x] = cnt;
  __syncthreads();
  for (int off = 1; off < SCAN_BS; off <<= 1) {  // Hillis-Steele inclusive
    int x = sm[threadIdx.x];
    int add = (threadIdx.x >= off) ? sm[threadIdx.x - off] : 0;
    __syncthreads();
    sm[threadIdx.x] = x + add;
    __syncthreads();
  }
  int r = blockoffs[blockIdx.x] + (sm[threadIdx.x] - cnt);  // exclusive rank
#pragma unroll
  for (int j = 0; j < ITEMS; ++j) {
    if (mbits & (1u << j)) {
      int i = base + j;
      int h = hslot_rank[i];       // read slot BEFORE overwriting with rank
      hslot_rank[i] = r;
      if (r < MAXV) {
        int lin = (int)entw[2u * (u32)h + 1u];   // high word = key
        int x = lin % GX;
        int t = lin / GX;
        int y = t % GY;
        int z = t / GY;
        out_coors[r * 3 + 0] = (float)z;
        out_coors[r * 3 + 1] = (float)y;
        out_coors[r * 3 + 2] = (float)x;
      }
      r++;
    }
  }
}

__global__ __launch_bounds__(256) void k_bucket(const int* __restrict__ lead,
                                                const int* __restrict__ rank,
                                                int* __restrict__ bcnt,
                                                int* __restrict__ bucket, int n) {
  int base = blockIdx.x * (256 * IB) + threadIdx.x;
#pragma unroll
  for (int j = 0; j < IB; ++j) {
    int i = base + j * 256;
    if (i < n) {
      int L = lead[i];
      if (L >= 0) {
        int r = rank[L];           // rank array = leader positions only
        if (r < MAXV) {
          int pos = atomicAdd(&bcnt[r], 1);
          if (pos < MAXP) bucket[r * MAXP + pos] = i;
        }
      }
    }
  }
}

// 32 lanes per slot. Lane r rank-selects the bucket entry of rank r
// (ascending original index) and writes voxels[s][r]; zero-fill the rest.
// Writes fully coalesced: lane r stores 16B at (s*32+r)*16.
__global__ __launch_bounds__(256) void k_emit(const float4* __restrict__ pts,
                                              const int* __restrict__ bcnt,
                                              const int* __restrict__ bucket,
                                              float4* __restrict__ out_voxels,
                                              float* __restrict__ out_npts) {
  __shared__ int sb[EMIT_SPB][MAXP];
  int grp = threadIdx.x >> 5;
  int r = threadIdx.x & 31;
  int s = blockIdx.x * EMIT_SPB + grp;
  if (s >= MAXV) return;

  int nfull = bcnt[s];
  int m = nfull < MAXP ? nfull : MAXP;
  if (r < m) sb[grp][r] = bucket[s * MAXP + r];
  __syncthreads();

  float4 row = make_float4(0.f, 0.f, 0.f, 0.f);
  if (r < m) {
    int mine = -1;
    for (int jj = 0; jj < m; ++jj) {   // entries unique; find rank==r
      int ej = sb[grp][jj];
      int rk = 0;
      for (int kk = 0; kk < m; ++kk) rk += (sb[grp][kk] < ej) ? 1 : 0;
      if (rk == r) mine = ej;
    }
    row = pts[mine];
  }
  out_voxels[(size_t)s * MAXP + r] = row;
  if (r == 0) out_npts[s] = (float)m;
}

extern "C" void kernel_launch(void* const* d_in, const int* in_sizes, int n_in,
                              void* d_out, int out_size, void* d_ws, size_t ws_size,
                              hipStream_t stream) {
  const float4* pts = (const float4*)d_in[0];
  int n = in_sizes[0] / 4;  // 2,000,000
  float* out = (float*)d_out;

  // Workspace layout (bytes); total ~63.9 MB
  char* ws = (char*)d_ws;
  u64* ent       = (u64*)(ws);                                    // 32 MB
  int* hslot     = (int*)(ws + (size_t)HSIZE * 8);                // 8 MB (becomes rank)
  int* lead      = (int*)(ws + (size_t)HSIZE * 8 + (size_t)n * 4);           // 8 MB
  int* blocksums = (int*)(ws + (size_t)HSIZE * 8 + (size_t)n * 8);           // 16 KB
  int* bcnt      = (int*)(ws + (size_t)HSIZE * 8 + (size_t)n * 8 + 16384);   // 480 KB
  int* bucket    = (int*)(ws + (size_t)HSIZE * 8 + (size_t)n * 8 + 16384 + (size_t)MAXV * 4);  // 15.36 MB

  float* out_voxels = out;                                     // 120000*32*4
  float* out_coors  = out + (size_t)MAXV * MAXP * 4;           // 120000*3
  float* out_npts   = out_coors + (size_t)MAXV * 3;            // 120000
  float* out_voxnum = out_npts + MAXV;                         // 1

  hipMemsetAsync(ent, 0xFF, (size_t)HSIZE * 8, stream);        // EMPTY64 everywhere
  hipMemsetAsync(bcnt, 0, (size_t)MAXV * 4, stream);
  hipMemsetAsync(out_coors, 0, ((size_t)MAXV * 3 + MAXV + 1) * sizeof(float), stream);

  int nb_ins  = (n + 256 * IB - 1) / (256 * IB);   // 1954
  int nb_scan = (n + CHUNK - 1) / CHUNK;           // 489 (<=512 required)

  k_insert<<<nb_ins, 256, 0, stream>>>(pts, ent, hslot, n);
  k_scan1<<<nb_scan, SCAN_BS, 0, stream>>>(hslot, (const u32*)ent, lead, blocksums, n);
  k_scan2<<<1, 512, 0, stream>>>(blocksums, out_voxnum, nb_scan);
  k_scan3<<<nb_scan, SCAN_BS, 0, stream>>>(lead, hslot, (const u32*)ent, blocksums, out_coors, n);
  k_bucket<<<nb_ins, 256, 0, stream>>>(lead, hslot /*rank*/, bcnt, bucket, n);
  k_emit<<<(MAXV + EMIT_SPB - 1) / EMIT_SPB, 256, 0, stream>>>(
      pts, bcnt, bucket, (float4*)out_voxels, out_npts);
}